// Round 10
// baseline (158.233 us; speedup 1.0000x reference)
//
#include <hip/hip_runtime.h>

#define H 512
#define WID 1024
#define HW (H*WID)
#define B 4
#define K 8
#define NB 256                  // histogram buckets (error <= 32*(2/NB)/2/3 = 0.042 << 2.47)
#define NBLK1 128               // k1 blocks per image

// ws word (4-byte) layout
#define OFF_LOSS  0
#define OFF_CTRC  8             // kC done-counter
#define OFF_FIN   128           // B*K*8 floats: a,bx,by,d0,cnt,pad  (words 128..384)
#define OFF_SPART 512           // B*K*NBLK1*5 floats = 20480
#define OFF_PART  21504         // B*G*K*NB u32 (pos<<16|cnt); G=256 -> 8 MB

static __device__ __forceinline__ float frcp(float x){ return __builtin_amdgcn_rcpf(x); }
static __device__ __forceinline__ float fexp2(float x){ return __builtin_amdgcn_exp2f(x); }
static __device__ __forceinline__ float ftanh(float x){
  return 1.0f - 2.0f * frcp(__expf(2.0f*x) + 1.0f);
}
static __device__ __forceinline__ float fsigmoid(float x){
  return frcp(1.0f + __expf(-x));
}

// ---------------- Kernel 1: per-(b,k) stats — O(px) LDS-atomic scatter ----------------
// Replaces the O(px*K) branchless scan (issue-bound, ~60 VALU/px) with 3 LDS
// atomics per foreground pixel: u64 pack (cnt<<45 | iy<<23 | ix) + f32 s + f32 s2.
// 512 blocks x 256 thr, 16 px/thread. Partials: 40 plain floats per block.
__global__ __launch_bounds__(256) void k1_stats(const float* __restrict__ pred,
                                                const int* __restrict__ inst,
                                                float* __restrict__ ws) {
  const int b = blockIdx.y;
  __shared__ unsigned long long tA[K];       // ix | iy<<23 | cnt<<45
  __shared__ float tS[K], tS2[K];
  if (threadIdx.x < K) { tA[threadIdx.x] = 0ull; tS[threadIdx.x] = 0.f; tS2[threadIdx.x] = 0.f; }
  __syncthreads();
  const float4* sig4 = (const float4*)(pred + (size_t)(8*b + 5) * HW);  // ch2 t=1
  const int4*   ins4 = (const int4*)(inst + (size_t)(2*b + 1) * HW);
  const int base4 = blockIdx.x * 1024;       // 1024 int4-groups (4096 px) per block
  #pragma unroll
  for (int g = 0; g < 4; g++) {
    const int q = base4 + threadIdx.x + 256*g;
    const int4   iv = ins4[q];
    const float4 sv = sig4[q];
    const int p = q * 4;                     // row-aligned: 4 elems share iy, ix+0..3
    const unsigned long long Ab = (unsigned long long)(unsigned)(p & 1023)
                                | ((unsigned long long)(unsigned)(p >> 10) << 23)
                                | (1ULL << 45);
    if (iv.x) { atomicAdd(&tA[iv.x-1], Ab+0); atomicAdd(&tS[iv.x-1], sv.x); atomicAdd(&tS2[iv.x-1], sv.x*sv.x); }
    if (iv.y) { atomicAdd(&tA[iv.y-1], Ab+1); atomicAdd(&tS[iv.y-1], sv.y); atomicAdd(&tS2[iv.y-1], sv.y*sv.y); }
    if (iv.z) { atomicAdd(&tA[iv.z-1], Ab+2); atomicAdd(&tS[iv.z-1], sv.z); atomicAdd(&tS2[iv.z-1], sv.z*sv.z); }
    if (iv.w) { atomicAdd(&tA[iv.w-1], Ab+3); atomicAdd(&tS[iv.w-1], sv.w); atomicAdd(&tS2[iv.w-1], sv.w*sv.w); }
  }
  __syncthreads();
  if (threadIdx.x < K) {
    const unsigned long long A = tA[threadIdx.x];
    const float cnt = (float)(unsigned)(A >> 45);
    const float sx  = (float)(unsigned)(A & 0x7FFFFFull)        * (2.0f/2047.0f);
    const float sy  = (float)(unsigned)((A >> 23) & 0x3FFFFFull) * (1.0f/1023.0f);
    float* r = ws + OFF_SPART + ((size_t)(b*K + threadIdx.x)*NBLK1 + blockIdx.x)*5;
    r[0]=cnt; r[1]=sx; r[2]=sy; r[3]=tS[threadIdx.x]; r[4]=tS2[threadIdx.x];
  }
}

// ---------------- Kernel 2: reduce spart, finalize log2-domain params + var loss ----------------
__global__ __launch_bounds__(256) void k2_fin(float* __restrict__ ws) {
  const int t = threadIdx.x;
  const int bk = t >> 3, s = t & 7;
  float a0=0.f,a1=0.f,a2=0.f,a3=0.f,a4=0.f;
  for (int j = 0; j < NBLK1/8; j++) {
    const float* p = ws + OFF_SPART + ((size_t)bk*NBLK1 + (s + 8*j))*5;
    a0+=p[0]; a1+=p[1]; a2+=p[2]; a3+=p[3]; a4+=p[4];
  }
  #pragma unroll
  for (int o=1;o<8;o<<=1){
    a0+=__shfl_xor(a0,o,64); a1+=__shfl_xor(a1,o,64); a2+=__shfl_xor(a2,o,64);
    a3+=__shfl_xor(a3,o,64); a4+=__shfl_xor(a4,o,64);
  }
  __shared__ float vloc[32];
  if (s == 0) {
    const float cnt=a0, sx=a1, sy=a2, ss=a3, ss2=a4;
    const float present = (cnt > 0.0f) ? 1.0f : 0.0f;
    const float safe = fmaxf(cnt, 1.0f);
    const float cx = sx/safe, cy = sy/safe, sm = ss/safe;
    const float var = (ss2 - 2.0f*sm*ss + sm*sm*cnt)/safe;   // N_SIGMA=1
    const float sexp = expf(10.0f * sm);
    const float L2E = 1.4426950408889634f;
    float* fin = ws + OFF_FIN + bk*8;
    fin[0] = -sexp*L2E;                       // a
    fin[1] =  2.0f*sexp*cx*L2E;               // bx
    fin[2] =  2.0f*sexp*cy*L2E;               // by
    fin[3] = -sexp*(cx*cx + cy*cy)*L2E + 8.0f;  // d0: +8 folds the x256 bucket scale
    fin[4] = cnt;
    vloc[bk] = present * 10.0f * var * (1.0f/3.0f);   // W_VAR=10, /(B-1)
  }
  __syncthreads();
  if (t == 0) {
    float v = 0.f;
    #pragma unroll
    for (int i = 0; i < 32; i++) v += vloc[i];
    atomicAdd(ws + OFF_LOSS, v);
  }
}

// ---------------- Kernel 3: main pass — 3-FMA log2 bucketing, 8KB LDS hist ----------------
template<int G>
__global__ __launch_bounds__(256) void k3_main(const float* __restrict__ pred,
                                               const int* __restrict__ inst,
                                               float* __restrict__ ws,
                                               unsigned int* __restrict__ part) {
  const int b = blockIdx.y, g = blockIdx.x;
  __shared__ unsigned int hist[K*NB];           // pos<<16 | cnt, 8 KiB
  for (int i = threadIdx.x; i < K*NB; i += 256) hist[i] = 0;
  float4 fr[K];
  #pragma unroll
  for (int k=0;k<K;k++){
    const float* fin = ws + OFF_FIN + (b*K + k)*8;
    fr[k] = make_float4(fin[0], fin[1], fin[2], fin[3]);  // {a,bx,by,d0}
  }
  __syncthreads();
  const float4* p0 = (const float4*)(pred + (size_t)(8*b+1)*HW);
  const float4* p1 = (const float4*)(pred + (size_t)(8*b+3)*HW);
  const float4* p3 = (const float4*)(pred + (size_t)(8*b+7)*HW);
  const int4*   in4 = (const int4*)(inst + (size_t)(2*b+1)*HW);
  float sAcc = 0.0f;
  constexpr int CH4 = HW / (G*4);               // int4-groups per block
  const int base4 = g * CH4;
  #pragma unroll
  for (int q0 = 0; q0 < CH4; q0 += 256) {
    const int idx = base4 + q0 + threadIdx.x;
    const int4   iv = in4[idx];
    const float4 f0 = p0[idx];
    const float4 f1 = p1[idx];
    const float4 f3 = p3[idx];
    const int p = idx * 4;
    const float xm0 = (float)(p & (WID-1)) * (2.0f/2047.0f);
    const float ym  = (float)(p >> 10)     * (1.0f/1023.0f);
    const int   ivv[4] = {iv.x, iv.y, iv.z, iv.w};
    const float a0v[4] = {f0.x, f0.y, f0.z, f0.w};
    const float a1v[4] = {f1.x, f1.y, f1.z, f1.w};
    const float a3v[4] = {f3.x, f3.y, f3.z, f3.w};
    #pragma unroll
    for (int e4 = 0; e4 < 4; e4++) {
      const int ivp = ivv[e4];
      const float px = ftanh(a0v[e4]) + xm0 + (float)e4*(2.0f/2047.0f);
      const float py = ftanh(a1v[e4]) + ym;
      const float sd = fsigmoid(a3v[e4]);
      const float t2 = px*px + py*py;
      float down = 0.0f;
      #pragma unroll
      for (int j=0;j<K;j++){
        const float u = fmaf(fr[j].x, t2, fmaf(fr[j].y, px, fmaf(fr[j].z, py, fr[j].w)));
        const float v = fexp2(u);                 // 256*dist in [0,256]
        int vi = (int)v; vi = (vi > NB-1) ? NB-1 : vi;
        const bool own = (ivp == j+1);
        const int bu = own ? (NB-1 - vi) : vi;
        if (own) down = v;
        atomicAdd(&hist[j*NB + bu], own ? 0x10001u : 1u);
      }
      const float d  = (ivp == 0) ? 0.0f : down * (1.0f/256.0f);
      const float df = sd - d;
      sAcc += df*df;                              // bg: sd^2; fg: (sd-dist)^2
    }
  }
  __syncthreads();
  // plain coalesced flush (px/block = HW/G <= 4096 < 65536: 16-bit fields safe)
  unsigned int* dst = part + ((size_t)b*G + g)*(K*NB);
  for (int i = threadIdx.x; i < K*NB; i += 256) dst[i] = hist[i];
  #pragma unroll
  for (int o=1;o<64;o<<=1) sAcc += __shfl_xor(sAcc, o, 64);
  __shared__ float wsum[4];
  if ((threadIdx.x & 63) == 0) wsum[threadIdx.x>>6] = sAcc;
  __syncthreads();
  if (threadIdx.x == 0) {
    const float tot = wsum[0]+wsum[1]+wsum[2]+wsum[3];
    atomicAdd(ws + OFF_LOSS, tot * (1.0f/((float)HW * 3.0f)));  // W_SEED /npix /(B-1)
  }
}

// ---------------- Kernel C: G-way gather + Lovász + output ----------------
__global__ __launch_bounds__(256) void kC_lovasz(const unsigned int* __restrict__ part,
                                                 float* __restrict__ ws,
                                                 float* __restrict__ out,
                                                 unsigned int* __restrict__ ctr, int G) {
  const int bk = blockIdx.x;                    // b*K + k
  const int b = bk >> 3, k = bk & 7;
  const int t = threadIdx.x, lane = t & 63, wv = t >> 6;
  const int bu = NB-1 - t;
  const unsigned int* base = part + (size_t)k*NB + bu;
  unsigned int rc = 0, rp = 0;
  #pragma unroll 8
  for (int g = 0; g < G; g++) {
    const unsigned int v = base[((size_t)b*G + g)*(K*NB)];
    rc += v & 0xFFFFu;
    rp += v >> 16;
  }
  const float cntF = ws[OFF_FIN + bk*8 + 4];
  int ic = (int)rc, ip = (int)rp;
  #pragma unroll
  for (int o=1;o<64;o<<=1){
    const int vc = __shfl_up(ic, o, 64);
    const int vp = __shfl_up(ip, o, 64);
    if (lane >= o) { ic += vc; ip += vp; }
  }
  __shared__ int wtc[4], wtp[4];
  if (lane == 63) { wtc[wv] = ic; wtp[wv] = ip; }
  __syncthreads();
  int offc = 0, offp = 0;
  for (int w = 0; w < wv; w++) { offc += wtc[w]; offp += wtp[w]; }
  int irun = offc + ic - (int)rc;               // exclusive prefixes
  int crun = offp + ip - (int)rp;
  double acc = 0.0;
  if (cntF > 0.0f && rc) {
    const double Pd = (double)cntF;
    const double jac0 = (irun==0) ? 0.0 : 1.0 - (Pd - crun)/(Pd + irun - crun);
    irun += (int)rc; crun += (int)rp;
    const double jac1 = 1.0 - (Pd - crun)/(Pd + irun - crun);
    acc = ((bu + 0.5) * (2.0/NB)) * (jac1 - jac0);
  }
  #pragma unroll
  for (int o=1;o<64;o<<=1) acc += __shfl_xor(acc, o, 64);
  __shared__ double racc[4];
  if (lane == 0) racc[wv] = acc;
  __syncthreads();
  if (t == 0) {
    const double tot = racc[0]+racc[1]+racc[2]+racc[3];
    atomicAdd(ws + OFF_LOSS, (float)(tot * (1.0/3.0)));   // W_INST=1, /(B-1)
  }
  __threadfence();
  __shared__ int lastB;
  if (t == 0) lastB = (atomicAdd(ctr, 1u) == (unsigned)(B*K - 1)) ? 1 : 0;
  __syncthreads();
  if (lastB && t == 0) {
    __threadfence();
    out[0] = atomicAdd(ws + OFF_LOSS, 0.0f);    // atomic fetch ensures coherent read
  }
}

extern "C" void kernel_launch(void* const* d_in, const int* in_sizes, int n_in,
                              void* d_out, int out_size, void* d_ws, size_t ws_size,
                              hipStream_t stream) {
  const float* pred = (const float*)d_in[0];
  const int*   inst = (const int*)d_in[1];
  float* ws  = (float*)d_ws;
  float* out = (float*)d_out;
  unsigned int* ctrC = ((unsigned int*)d_ws) + OFF_CTRC;
  unsigned int* part = ((unsigned int*)d_ws) + OFF_PART;
  int G = 256;
  if (ws_size < ((size_t)OFF_PART + (size_t)B*256*K*NB)*4) G = 128;
  hipMemsetAsync(d_ws, 0, 2048, stream);     // zero LOSS + ctr + FIN
  k1_stats<<<dim3(NBLK1,B), 256, 0, stream>>>(pred, inst, ws);
  k2_fin  <<<1, 256, 0, stream>>>(ws);
  if (G == 256) k3_main<256><<<dim3(256,B), 256, 0, stream>>>(pred, inst, ws, part);
  else          k3_main<128><<<dim3(128,B), 256, 0, stream>>>(pred, inst, ws, part);
  kC_lovasz<<<B*K, 256, 0, stream>>>(part, ws, out, ctrC, G);
}

// Round 11
// 145.967 us; speedup vs baseline: 1.0840x; 1.0840x over previous
//
#include <hip/hip_runtime.h>

#define H 512
#define WID 1024
#define HW (H*WID)
#define B 4
#define K 8
#define NB 256                  // histogram buckets (error <= 32/(3*NB) = 0.042 << 2.47)
#define NBLK1 128               // k1 blocks per image

// ws word (4-byte) layout
#define OFF_LOSS  0
#define OFF_CTRC  8             // kC done-counter
#define OFF_FIN   128           // B*K*8 floats: a,bx,by,d0,cnt,pad  (words 128..384)
#define OFF_SPART 512           // B*K*NBLK1*5 floats = 20480
#define OFF_PART  21504         // B*G*K*NB u32 (pos<<16|cnt); G=256 -> 8.4 MB

static __device__ __forceinline__ float frcp(float x){ return __builtin_amdgcn_rcpf(x); }
static __device__ __forceinline__ float fexp2(float x){ return __builtin_amdgcn_exp2f(x); }
static __device__ __forceinline__ float ftanh(float x){
  return 1.0f - 2.0f * frcp(__expf(2.0f*x) + 1.0f);
}
static __device__ __forceinline__ float fsigmoid(float x){
  return frcp(1.0f + __expf(-x));
}

// ---------------- Kernel 1: per-(b,k) stats — LDS staged, branchless (R8-proven) ----------------
__global__ __launch_bounds__(512) void k1_stats(const float* __restrict__ pred,
                                                const int* __restrict__ inst,
                                                float* __restrict__ ws) {
  const int b = blockIdx.y;
  __shared__ int4   ti[1024];
  __shared__ float4 ts[1024];
  __shared__ float  part5[K][5];
  const float4* sig4 = (const float4*)(pred + (size_t)(8*b + 5) * HW);  // ch2 t=1
  const int4*   ins4 = (const int4*)(inst + (size_t)(2*b + 1) * HW);
  const int base4 = blockIdx.x * 1024;     // 1024 int4-groups (4096 px) per block
  #pragma unroll
  for (int i = 0; i < 2; i++) {
    const int q = threadIdx.x + i*512;
    ti[q] = ins4[base4 + q];
    ts[q] = sig4[base4 + q];
  }
  __syncthreads();
  const int wv = threadIdx.x >> 6, lane = threadIdx.x & 63;
  const int kk = wv + 1;
  float cnt=0.f, sx=0.f, sy=0.f, ss=0.f, ss2=0.f;
  #pragma unroll
  for (int j = 0; j < 16; j++) {
    const int q = lane + 64*j;
    const int4   iv = ti[q];
    const float4 sv = ts[q];
    const int p = (base4 + q) * 4;
    const float xm0 = (float)(p & (WID-1)) * (2.0f/2047.0f);
    const float ym  = (float)(p >> 10)     * (1.0f/1023.0f);
    const float m0 = (iv.x==kk)?1.f:0.f, m1=(iv.y==kk)?1.f:0.f,
                m2 = (iv.z==kk)?1.f:0.f, m3=(iv.w==kk)?1.f:0.f;
    const float msum = (m0+m1)+(m2+m3);
    cnt += msum;
    sx  += msum*xm0 + (m1 + 2.0f*m2 + 3.0f*m3)*(2.0f/2047.0f);
    sy  += msum*ym;
    ss  += m0*sv.x + m1*sv.y + m2*sv.z + m3*sv.w;
    ss2 += m0*sv.x*sv.x + m1*sv.y*sv.y + m2*sv.z*sv.z + m3*sv.w*sv.w;
  }
  #pragma unroll
  for (int o=1;o<64;o<<=1){
    cnt+=__shfl_xor(cnt,o,64);
    sx +=__shfl_xor(sx, o,64);
    sy +=__shfl_xor(sy, o,64);
    ss +=__shfl_xor(ss, o,64);
    ss2+=__shfl_xor(ss2,o,64);
  }
  if (lane == 0) {
    part5[wv][0]=cnt; part5[wv][1]=sx; part5[wv][2]=sy; part5[wv][3]=ss; part5[wv][4]=ss2;
  }
  __syncthreads();
  if (threadIdx.x < K*5) {
    const int w = threadIdx.x / 5, c = threadIdx.x % 5;
    ws[OFF_SPART + ((size_t)(b*K + w)*NBLK1 + blockIdx.x)*5 + c] = part5[w][c];
  }
}

// ---------------- Kernel 2: reduce spart, finalize log2-domain params + var loss ----------------
__global__ __launch_bounds__(256) void k2_fin(float* __restrict__ ws) {
  const int t = threadIdx.x;
  const int bk = t >> 3, s = t & 7;
  float a0=0.f,a1=0.f,a2=0.f,a3=0.f,a4=0.f;
  for (int j = 0; j < NBLK1/8; j++) {
    const float* p = ws + OFF_SPART + ((size_t)bk*NBLK1 + (s + 8*j))*5;
    a0+=p[0]; a1+=p[1]; a2+=p[2]; a3+=p[3]; a4+=p[4];
  }
  #pragma unroll
  for (int o=1;o<8;o<<=1){
    a0+=__shfl_xor(a0,o,64); a1+=__shfl_xor(a1,o,64); a2+=__shfl_xor(a2,o,64);
    a3+=__shfl_xor(a3,o,64); a4+=__shfl_xor(a4,o,64);
  }
  __shared__ float vloc[32];
  if (s == 0) {
    const float cnt=a0, sx=a1, sy=a2, ss=a3, ss2=a4;
    const float present = (cnt > 0.0f) ? 1.0f : 0.0f;
    const float safe = fmaxf(cnt, 1.0f);
    const float cx = sx/safe, cy = sy/safe, sm = ss/safe;
    const float var = (ss2 - 2.0f*sm*ss + sm*sm*cnt)/safe;   // N_SIGMA=1
    const float sexp = expf(10.0f * sm);
    const float L2E = 1.4426950408889634f;
    float* fin = ws + OFF_FIN + bk*8;
    fin[0] = -sexp*L2E;                       // a
    fin[1] =  2.0f*sexp*cx*L2E;               // bx
    fin[2] =  2.0f*sexp*cy*L2E;               // by
    fin[3] = -sexp*(cx*cx + cy*cy)*L2E + 8.0f;  // d0: +8 folds the x256 bucket scale
    fin[4] = cnt;
    vloc[bk] = present * 10.0f * var * (1.0f/3.0f);   // W_VAR=10, /(B-1)
  }
  __syncthreads();
  if (t == 0) {
    float v = 0.f;
    #pragma unroll
    for (int i = 0; i < 32; i++) v += vloc[i];
    atomicAdd(ws + OFF_LOSS, v);
  }
}

// ---------------- Kernel 3: main pass — 3-FMA log2 bucketing, skip far-pixel atomics ----------------
// Non-own contributions with vi==0 (dist < 1/256) are NOT written; kC
// reconstructs bucket-0 counts exactly from the deficit HW - sum(cnt).
template<int G>
__global__ __launch_bounds__(256) void k3_main(const float* __restrict__ pred,
                                               const int* __restrict__ inst,
                                               float* __restrict__ ws,
                                               unsigned int* __restrict__ part) {
  const int b = blockIdx.y, g = blockIdx.x;
  __shared__ unsigned int hist[K*NB];           // pos<<16 | cnt, 8 KiB
  for (int i = threadIdx.x; i < K*NB; i += 256) hist[i] = 0;
  float4 fr[K];
  #pragma unroll
  for (int k=0;k<K;k++){
    const float* fin = ws + OFF_FIN + (b*K + k)*8;
    fr[k] = make_float4(fin[0], fin[1], fin[2], fin[3]);  // {a,bx,by,d0}
  }
  __syncthreads();
  const float4* p0 = (const float4*)(pred + (size_t)(8*b+1)*HW);
  const float4* p1 = (const float4*)(pred + (size_t)(8*b+3)*HW);
  const float4* p3 = (const float4*)(pred + (size_t)(8*b+7)*HW);
  const int4*   in4 = (const int4*)(inst + (size_t)(2*b+1)*HW);
  float sAcc = 0.0f;
  constexpr int CH4 = HW / (G*4);               // int4-groups per block
  const int base4 = g * CH4;
  #pragma unroll
  for (int q0 = 0; q0 < CH4; q0 += 256) {
    const int idx = base4 + q0 + threadIdx.x;
    const int4   iv = in4[idx];
    const float4 f0 = p0[idx];
    const float4 f1 = p1[idx];
    const float4 f3 = p3[idx];
    const int p = idx * 4;
    const float xm0 = (float)(p & (WID-1)) * (2.0f/2047.0f);
    const float ym  = (float)(p >> 10)     * (1.0f/1023.0f);
    const int   ivv[4] = {iv.x, iv.y, iv.z, iv.w};
    const float a0v[4] = {f0.x, f0.y, f0.z, f0.w};
    const float a1v[4] = {f1.x, f1.y, f1.z, f1.w};
    const float a3v[4] = {f3.x, f3.y, f3.z, f3.w};
    #pragma unroll
    for (int e4 = 0; e4 < 4; e4++) {
      const int ivp = ivv[e4];
      const float px = ftanh(a0v[e4]) + xm0 + (float)e4*(2.0f/2047.0f);
      const float py = ftanh(a1v[e4]) + ym;
      const float sd = fsigmoid(a3v[e4]);
      const float t2 = px*px + py*py;
      float down = 0.0f;
      #pragma unroll
      for (int j=0;j<K;j++){
        const float u = fmaf(fr[j].x, t2, fmaf(fr[j].y, px, fmaf(fr[j].z, py, fr[j].w)));
        const float v = fexp2(u);                 // 256*dist in [0,256]
        int vi = (int)v; vi = (vi > NB-1) ? NB-1 : vi;
        const bool own = (ivp == j+1);
        const int bu = own ? (NB-1 - vi) : vi;
        if (own) down = v;
        if (own || vi > 0)                        // skip far non-own (bucket 0): reconstructed in kC
          atomicAdd(&hist[j*NB + bu], own ? 0x10001u : 1u);
      }
      const float d  = (ivp == 0) ? 0.0f : down * (1.0f/256.0f);
      const float df = sd - d;
      sAcc += df*df;                              // bg: sd^2; fg: (sd-dist)^2
    }
  }
  __syncthreads();
  // plain coalesced flush (px/block = HW/G <= 4096 < 65536: 16-bit fields safe)
  unsigned int* dst = part + ((size_t)b*G + g)*(K*NB);
  for (int i = threadIdx.x; i < K*NB; i += 256) dst[i] = hist[i];
  #pragma unroll
  for (int o=1;o<64;o<<=1) sAcc += __shfl_xor(sAcc, o, 64);
  __shared__ float wsum[4];
  if ((threadIdx.x & 63) == 0) wsum[threadIdx.x>>6] = sAcc;
  __syncthreads();
  if (threadIdx.x == 0) {
    const float tot = wsum[0]+wsum[1]+wsum[2]+wsum[3];
    atomicAdd(ws + OFF_LOSS, tot * (1.0f/((float)HW * 3.0f)));  // W_SEED /npix /(B-1)
  }
}

// ---------------- Kernel C: G-way gather + Lovász + output (deficit-reconstructing) ----------------
__global__ __launch_bounds__(256) void kC_lovasz(const unsigned int* __restrict__ part,
                                                 float* __restrict__ ws,
                                                 float* __restrict__ out,
                                                 unsigned int* __restrict__ ctr, int G) {
  const int bk = blockIdx.x;                    // b*K + k
  const int b = bk >> 3, k = bk & 7;
  const int t = threadIdx.x, lane = t & 63, wv = t >> 6;
  const int bu = NB-1 - t;                      // thread 255 owns bucket 0 (last, descending)
  const unsigned int* base = part + (size_t)k*NB + bu;
  unsigned int rc = 0, rp = 0;
  #pragma unroll 8
  for (int g = 0; g < G; g++) {
    const unsigned int v = base[((size_t)b*G + g)*(K*NB)];
    rc += v & 0xFFFFu;
    rp += v >> 16;
  }
  const float cntF = ws[OFF_FIN + bk*8 + 4];
  int ic = (int)rc, ip = (int)rp;
  #pragma unroll
  for (int o=1;o<64;o<<=1){
    const int vc = __shfl_up(ic, o, 64);
    const int vp = __shfl_up(ip, o, 64);
    if (lane >= o) { ic += vc; ip += vp; }
  }
  __shared__ int wtc[4], wtp[4];
  if (lane == 63) { wtc[wv] = ic; wtp[wv] = ip; }
  __syncthreads();
  int offc = 0, offp = 0;
  for (int w = 0; w < wv; w++) { offc += wtc[w]; offp += wtp[w]; }
  int irun = offc + ic - (int)rc;               // exclusive prefixes
  int crun = offp + ip - (int)rp;
  // exact reconstruction of skipped bucket-0 non-own entries:
  // total observed = wtc[0..3]; deficit = HW - total goes to bucket 0 (the last
  // position) -> only its own jac term changes, no other prefix is affected.
  if (bu == 0) {
    const int totC = wtc[0]+wtc[1]+wtc[2]+wtc[3];
    rc += (unsigned)(HW - totC);
  }
  double acc = 0.0;
  if (cntF > 0.0f && rc) {
    const double Pd = (double)cntF;
    const double jac0 = (irun==0) ? 0.0 : 1.0 - (Pd - crun)/(Pd + irun - crun);
    irun += (int)rc; crun += (int)rp;
    const double jac1 = 1.0 - (Pd - crun)/(Pd + irun - crun);
    acc = ((bu + 0.5) * (2.0/NB)) * (jac1 - jac0);
  }
  #pragma unroll
  for (int o=1;o<64;o<<=1) acc += __shfl_xor(acc, o, 64);
  __shared__ double racc[4];
  if (lane == 0) racc[wv] = acc;
  __syncthreads();
  if (t == 0) {
    const double tot = racc[0]+racc[1]+racc[2]+racc[3];
    atomicAdd(ws + OFF_LOSS, (float)(tot * (1.0/3.0)));   // W_INST=1, /(B-1)
  }
  __threadfence();
  __shared__ int lastB;
  if (t == 0) lastB = (atomicAdd(ctr, 1u) == (unsigned)(B*K - 1)) ? 1 : 0;
  __syncthreads();
  if (lastB && t == 0) {
    __threadfence();
    out[0] = atomicAdd(ws + OFF_LOSS, 0.0f);    // atomic fetch ensures coherent read
  }
}

extern "C" void kernel_launch(void* const* d_in, const int* in_sizes, int n_in,
                              void* d_out, int out_size, void* d_ws, size_t ws_size,
                              hipStream_t stream) {
  const float* pred = (const float*)d_in[0];
  const int*   inst = (const int*)d_in[1];
  float* ws  = (float*)d_ws;
  float* out = (float*)d_out;
  unsigned int* ctrC = ((unsigned int*)d_ws) + OFF_CTRC;
  unsigned int* part = ((unsigned int*)d_ws) + OFF_PART;
  int G = 256;
  if (ws_size < ((size_t)OFF_PART + (size_t)B*256*K*NB)*4) G = 128;
  hipMemsetAsync(d_ws, 0, 2048, stream);     // zero LOSS + ctr + FIN
  k1_stats<<<dim3(NBLK1,B), 512, 0, stream>>>(pred, inst, ws);
  k2_fin  <<<1, 256, 0, stream>>>(ws);
  if (G == 256) k3_main<256><<<dim3(256,B), 256, 0, stream>>>(pred, inst, ws, part);
  else          k3_main<128><<<dim3(128,B), 256, 0, stream>>>(pred, inst, ws, part);
  kC_lovasz<<<B*K, 256, 0, stream>>>(part, ws, out, ctrC, G);
}